// Round 10
// baseline (599.347 us; speedup 1.0000x reference)
//
#include <hip/hip_runtime.h>

// ---------------------------------------------------------------------------
// MultiHeadAttention (B=1, N=2925, D_MODEL=1536, 12 heads x 128) on gfx950.
// prep(convert x + transpose W, merged) -> QKV bf16 GEMM (256x256 dbuf
// counted-vmcnt pipeline) -> postproj(RMSNorm+RoPE Q,K + V transpose, merged)
// -> NO-SPLIT flash attention (swapped-QK^T, K dbuf LDS, V direct-from-L2,
// 2 barriers/tile, epilogue normalization) -> O GEMM (128^2).
// ---------------------------------------------------------------------------

#define N_TOK 2925
#define DMODEL 1536
#define NHEAD 12
#define HDIM 128
#define VT_STRIDE 2944        // N_TOK padded to x64; pad MUST be zeroed (NaN hazard)

typedef __attribute__((ext_vector_type(8))) __bf16 bf16x8;
typedef __attribute__((ext_vector_type(4))) float floatx4;

#define MFMA(a, b, c) __builtin_amdgcn_mfma_f32_16x16x32_bf16((a), (b), (c), 0, 0, 0)

static __device__ __forceinline__ unsigned short f2bf(float f) {
    unsigned u = __builtin_bit_cast(unsigned, f);
    return (unsigned short)((u + 0x7fffu + ((u >> 16) & 1u)) >> 16);
}

// async global->LDS 16B/lane (emits global_load_lds_dwordx4).
// LDS dest MUST be wave-uniform-base + lane*16.
static __device__ __forceinline__ void gload_lds16(const unsigned short* g, unsigned short* l) {
    __builtin_amdgcn_global_load_lds((const __attribute__((address_space(1))) void*)g,
                                     (__attribute__((address_space(3))) void*)l, 16, 0, 0);
}

// ------------------- merged prep: W transposes (blocks 0..9215) + x convert
__global__ __launch_bounds__(256) void k_prep(const float* __restrict__ W0,
                                              const float* __restrict__ W1,
                                              const float* __restrict__ W2,
                                              const float* __restrict__ W3,
                                              unsigned short* __restrict__ Wt,
                                              const float* __restrict__ x,
                                              unsigned short* __restrict__ xb, int n) {
    const int b = blockIdx.x;
    if (b < 9216) {                                    // ---- transpose role
        __shared__ float tile[32][33];
        const int bz = b / 2304, rem = b % 2304;
        const int byi = rem / 48, bxi = rem % 48;
        const float* W = bz == 0 ? W0 : bz == 1 ? W1 : bz == 2 ? W2 : W3;
        unsigned short* out = Wt + (size_t)bz * DMODEL * DMODEL;
        const int tx = threadIdx.x & 31, ty = threadIdx.x >> 5;   // 32 x 8
        const int bx = bxi * 32, by = byi * 32;
#pragma unroll
        for (int i = 0; i < 4; i++)
            tile[ty + 8 * i][tx] = W[(size_t)(by + ty + 8 * i) * DMODEL + bx + tx];
        __syncthreads();
#pragma unroll
        for (int i = 0; i < 4; i++)
            out[(size_t)(bx + ty + 8 * i) * DMODEL + by + tx] = f2bf(tile[tx][ty + 8 * i]);
    } else {                                           // ---- convert role
        int i = ((b - 9216) * 256 + threadIdx.x) * 4;
        if (i < n) {
            float4 v = *(const float4*)(x + i);
            uint2 o;
            o.x = (unsigned)f2bf(v.x) | ((unsigned)f2bf(v.y) << 16);
            o.y = (unsigned)f2bf(v.z) | ((unsigned)f2bf(v.w) << 16);
            *(uint2*)(xb + i) = o;
        }
    }
}

// ---------------------- QKV GEMM: 256x256 tile, BK=64, 8 waves, dbuf pipeline
__global__ __launch_bounds__(512, 2) void k_gemm_qkv(const unsigned short* __restrict__ A,
                                                     const unsigned short* __restrict__ BtBase,
                                                     const float* __restrict__ b0,
                                                     const float* __restrict__ b1,
                                                     const float* __restrict__ b2,
                                                     float* __restrict__ Cbase, int M) {
    __shared__ __align__(16) unsigned short As[2][256 * 64];   // 2 x 32 KiB
    __shared__ __align__(16) unsigned short Bs[2][256 * 64];   // 2 x 32 KiB

    // XCD swizzle: nb = 216 = 8*27 exact
    const int blin = blockIdx.x + 6 * (blockIdx.y + 12 * (int)blockIdx.z);
    const int wg = (blin & 7) * 27 + (blin >> 3);
    const int z = wg / 72, rem = wg % 72, mt = rem / 6, ntile = rem % 6;
    const unsigned short* Bt = BtBase + (size_t)z * DMODEL * DMODEL;
    const float* bias = (z == 0) ? b0 : (z == 1) ? b1 : b2;
    float* C = Cbase + (size_t)z * M * DMODEL;
    const int m0 = mt * 256, n0 = ntile * 256;

    const int tid = threadIdx.x;
    const int wave = tid >> 6, lane = tid & 63, quad = lane >> 4, l16 = lane & 15;
    const int x7 = l16 & 7;
    const int wm = wave >> 2, wn = wave & 3;

    const int koff0 = ((quad) ^ x7) * 8;
    const int koff1 = ((4 + quad) ^ x7) * 8;
    const int sl = tid & 7;

    floatx4 acc[8][4] = {};

    const unsigned short* Abase = A + (size_t)m0 * DMODEL;
    const unsigned short* Bbase = Bt + (size_t)n0 * DMODEL;

    auto stageB = [&](int buf, int h, int kt) {
#pragma unroll
        for (int i = 0; i < 2; i++) {
            int d = tid + 512 * i;
            int row = h * 128 + (d >> 3);
            int c = sl ^ (row & 7);
            gload_lds16(Bbase + (size_t)row * DMODEL + kt * 64 + c * 8,
                        &Bs[buf][(row * 8 + sl) * 8]);
        }
    };
    auto stageA = [&](int buf, int h, int kt) {
#pragma unroll
        for (int i = 0; i < 2; i++) {
            int d = tid + 512 * i;
            int r7 = d >> 3;
            int row = (r7 & 63) + h * 64 + (r7 >> 6) * 128;
            int c = sl ^ (row & 7);
            gload_lds16(Abase + (size_t)row * DMODEL + kt * 64 + c * 8,
                        &As[buf][(row * 8 + sl) * 8]);
        }
    };

    stageB(0, 0, 0); stageB(0, 1, 0); stageA(0, 0, 0); stageA(0, 1, 0);

    const int NT = DMODEL / 64;                                  // 24
    for (int t = 0; t < NT; t++) {
        const int c = t & 1, sb = c ^ 1;
        const int ts = (t + 1 < NT) ? t + 1 : NT - 1;

        asm volatile("s_waitcnt vmcnt(2)" ::: "memory");
        __builtin_amdgcn_sched_barrier(0);
        __builtin_amdgcn_s_barrier();

        bf16x8 af[4], bfm[4];
#pragma unroll
        for (int m = 0; m < 4; m++)
            af[m] = *(const bf16x8*)&As[c][(wm * 128 + m * 16 + l16) * 64 + koff0];
#pragma unroll
        for (int n = 0; n < 4; n++)
            bfm[n] = *(const bf16x8*)&Bs[c][(wn * 64 + n * 16 + l16) * 64 + koff0];
        stageB(sb, 0, ts);
        __builtin_amdgcn_s_barrier();
        __builtin_amdgcn_s_setprio(1);
#pragma unroll
        for (int m = 0; m < 4; m++)
#pragma unroll
            for (int n = 0; n < 4; n++)
                acc[m][n] = MFMA(af[m], bfm[n], acc[m][n]);
        __builtin_amdgcn_s_setprio(0);
        __builtin_amdgcn_sched_barrier(0);

        asm volatile("s_waitcnt vmcnt(2)" ::: "memory");
        __builtin_amdgcn_sched_barrier(0);
        __builtin_amdgcn_s_barrier();

        bf16x8 af2[4];
#pragma unroll
        for (int m = 0; m < 4; m++)
            af2[m] = *(const bf16x8*)&As[c][(wm * 128 + 64 + m * 16 + l16) * 64 + koff0];
        stageB(sb, 1, ts);
        __builtin_amdgcn_s_barrier();
        __builtin_amdgcn_s_setprio(1);
#pragma unroll
        for (int m = 0; m < 4; m++)
#pragma unroll
            for (int n = 0; n < 4; n++)
                acc[4 + m][n] = MFMA(af2[m], bfm[n], acc[4 + m][n]);
        __builtin_amdgcn_s_setprio(0);
        __builtin_amdgcn_sched_barrier(0);

#pragma unroll
        for (int m = 0; m < 4; m++)
            af[m] = *(const bf16x8*)&As[c][(wm * 128 + m * 16 + l16) * 64 + koff1];
#pragma unroll
        for (int n = 0; n < 4; n++)
            bfm[n] = *(const bf16x8*)&Bs[c][(wn * 64 + n * 16 + l16) * 64 + koff1];
        stageA(sb, 0, ts);
        __builtin_amdgcn_s_barrier();
        __builtin_amdgcn_s_setprio(1);
#pragma unroll
        for (int m = 0; m < 4; m++)
#pragma unroll
            for (int n = 0; n < 4; n++)
                acc[m][n] = MFMA(af[m], bfm[n], acc[m][n]);
        __builtin_amdgcn_s_setprio(0);
        __builtin_amdgcn_sched_barrier(0);

#pragma unroll
        for (int m = 0; m < 4; m++)
            af2[m] = *(const bf16x8*)&As[c][(wm * 128 + 64 + m * 16 + l16) * 64 + koff1];
        stageA(sb, 1, ts);
        __builtin_amdgcn_s_barrier();
        __builtin_amdgcn_s_setprio(1);
#pragma unroll
        for (int m = 0; m < 4; m++)
#pragma unroll
            for (int n = 0; n < 4; n++)
                acc[4 + m][n] = MFMA(af2[m], bfm[n], acc[4 + m][n]);
        __builtin_amdgcn_s_setprio(0);
        __builtin_amdgcn_sched_barrier(0);
    }

#pragma unroll
    for (int n = 0; n < 4; n++) {
        int cg = n0 + wn * 64 + n * 16 + l16;
        float bv = bias[cg];
#pragma unroll
        for (int m = 0; m < 8; m++) {
            int rbase = m0 + wm * 128 + m * 16 + quad * 4;
#pragma unroll
            for (int r = 0; r < 4; r++) {
                int rg = rbase + r;
                if (rg < M) C[(size_t)rg * DMODEL + cg] = acc[m][n][r] + bv;
            }
        }
    }
}

// ------------------------------------------------------------ bf16 MFMA GEMM
// m97 structure (used for the O projection): unpadded stride-32 LDS tiles.
__global__ __launch_bounds__(256, 3) void k_gemm(const unsigned short* __restrict__ A,
                                                 const unsigned short* __restrict__ BtBase,
                                                 const float* __restrict__ b0,
                                                 const float* __restrict__ b1,
                                                 const float* __restrict__ b2,
                                                 float* __restrict__ Cbase, int M) {
    const int nbx = gridDim.x, nxy = gridDim.x * gridDim.y;
    const int nb = nxy * gridDim.z;
    const int blin = blockIdx.x + nbx * (blockIdx.y + gridDim.y * blockIdx.z);
    const int q8 = nb >> 3, r8 = nb & 7, xcd = blin & 7, idx = blin >> 3;
    const int wg = (xcd < r8) ? xcd * (q8 + 1) + idx
                              : r8 * (q8 + 1) + (xcd - r8) * q8 + idx;
    const int z = wg / nxy;
    const int rem = wg % nxy;
    const int bym = rem / nbx, bxn = rem % nbx;

    const unsigned short* Bt = BtBase + (size_t)z * DMODEL * DMODEL;
    const float* bias = (z == 0) ? b0 : (z == 1) ? b1 : b2;
    float* C = Cbase + (size_t)z * M * DMODEL;

    __shared__ __align__(16) unsigned short As[128 * 32];
    __shared__ __align__(16) unsigned short Bs[128 * 32];

    const int tid = threadIdx.x;
    const int wave = tid >> 6, lane = tid & 63, quad = lane >> 4, l16 = lane & 15;
    const int wr = wave >> 1, wc = wave & 1;
    const int m0 = bym * 128, n0 = bxn * 128;
    const int r4 = tid >> 2, c4 = (tid & 3) * 8;

    floatx4 acc[4][4] = {};

    for (int k0 = 0; k0 < DMODEL; k0 += 32) {
        gload_lds16(A + (size_t)(m0 + r4) * DMODEL + k0 + c4,       &As[r4 * 32 + c4]);
        gload_lds16(A + (size_t)(m0 + r4 + 64) * DMODEL + k0 + c4,  &As[(r4 + 64) * 32 + c4]);
        gload_lds16(Bt + (size_t)(n0 + r4) * DMODEL + k0 + c4,      &Bs[r4 * 32 + c4]);
        gload_lds16(Bt + (size_t)(n0 + r4 + 64) * DMODEL + k0 + c4, &Bs[(r4 + 64) * 32 + c4]);
        __syncthreads();

        bf16x8 af[4], bfm[4];
#pragma unroll
        for (int i = 0; i < 4; i++)
            af[i] = *(const bf16x8*)&As[(wr * 64 + i * 16 + l16) * 32 + quad * 8];
#pragma unroll
        for (int j = 0; j < 4; j++)
            bfm[j] = *(const bf16x8*)&Bs[(wc * 64 + j * 16 + l16) * 32 + quad * 8];
#pragma unroll
        for (int i = 0; i < 4; i++)
#pragma unroll
            for (int j = 0; j < 4; j++)
                acc[i][j] = MFMA(af[i], bfm[j], acc[i][j]);
        __syncthreads();
    }

#pragma unroll
    for (int j = 0; j < 4; j++) {
        int cg = n0 + wc * 64 + j * 16 + l16;
        float bv = bias[cg];
#pragma unroll
        for (int i = 0; i < 4; i++) {
            int rbase = m0 + wr * 64 + i * 16 + quad * 4;
#pragma unroll
            for (int r = 0; r < 4; r++) {
                int rg = rbase + r;
                if (rg < M) C[(size_t)rg * DMODEL + cg] = acc[i][j][r] + bv;
            }
        }
    }
}

// ---------- merged postproj: RMSNorm+3D RoPE (blocks 0..2924) + V transpose
__global__ __launch_bounds__(256) void k_postproj(const float* __restrict__ Qf,
                                                  const float* __restrict__ Kf,
                                                  const float* __restrict__ Vf,
                                                  const float* __restrict__ qsc,
                                                  const float* __restrict__ ksc,
                                                  const float* __restrict__ ft,
                                                  const float* __restrict__ fh,
                                                  const float* __restrict__ fw,
                                                  unsigned short* __restrict__ qb,
                                                  unsigned short* __restrict__ kb,
                                                  unsigned short* __restrict__ vt) {
    const int blk = blockIdx.x;
    if (blk >= N_TOK) {                                // ---- V transpose role
        __shared__ float tile[32][33];
        const int v = blk - N_TOK;                     // 0..4415
        const int bxi = v % 92, byi = (v / 92) % 4, head = v / 368;
        const int t0 = bxi * 32, d0 = byi * 32;
        const int tx = threadIdx.x & 31, ty = threadIdx.x >> 5;   // 32 x 8
#pragma unroll
        for (int i = 0; i < 4; i++) {
            int t = t0 + ty + 8 * i;
            tile[ty + 8 * i][tx] = (t < N_TOK) ? Vf[(size_t)t * DMODEL + head * HDIM + d0 + tx] : 0.f;
        }
        __syncthreads();
        int t = t0 + tx;                               // < VT_STRIDE always
#pragma unroll
        for (int i = 0; i < 4; i++)
            vt[((size_t)head * HDIM + d0 + ty + 8 * i) * VT_STRIDE + t] = f2bf(tile[tx][ty + 8 * i]);
        return;
    }

    // ---- norm+rope role
    const int n = blk;
    const int tid = threadIdx.x, wave = tid >> 6, lane = tid & 63;
    const int t_i = n / 225, rem = n % 225, h_i = rem / 15, w_i = rem % 15;
    const float att_scale = 0.08838834764831845f * 1.4426950408889634f;  // 1/sqrt(128)*log2e

    float2 qv[3], kv[3];
    float sq = 0.f, sk = 0.f;
#pragma unroll
    for (int c = 0; c < 3; c++) {
        int p = tid + 256 * c;
        qv[c] = *(const float2*)(Qf + (size_t)n * DMODEL + 2 * p);
        kv[c] = *(const float2*)(Kf + (size_t)n * DMODEL + 2 * p);
        sq += qv[c].x * qv[c].x + qv[c].y * qv[c].y;
        sk += kv[c].x * kv[c].x + kv[c].y * kv[c].y;
    }
#pragma unroll
    for (int off = 32; off >= 1; off >>= 1) {
        sq += __shfl_xor(sq, off, 64);
        sk += __shfl_xor(sk, off, 64);
    }
    __shared__ float red[2][4];
    if (lane == 0) { red[0][wave] = sq; red[1][wave] = sk; }
    __syncthreads();
    sq = red[0][0] + red[0][1] + red[0][2] + red[0][3];
    sk = red[1][0] + red[1][1] + red[1][2] + red[1][3];
    const float rq = rsqrtf(sq * (1.f / 1536.f) + 1e-6f) * att_scale;
    const float rk = rsqrtf(sk * (1.f / 1536.f) + 1e-6f);

#pragma unroll
    for (int c = 0; c < 3; c++) {
        int p = tid + 256 * c;
        int hd = p >> 6, pl = p & 63, dd = 2 * pl;
        float cs, sn;
        if (pl < 22)      { cs = ft[t_i * 44 + 2 * pl];        sn = ft[t_i * 44 + 2 * pl + 1]; }
        else if (pl < 43) { int pp = pl - 22; cs = fh[h_i * 42 + 2 * pp]; sn = fh[h_i * 42 + 2 * pp + 1]; }
        else              { int pp = pl - 43; cs = fw[w_i * 42 + 2 * pp]; sn = fw[w_i * 42 + 2 * pp + 1]; }
        int hidx = hd * 128 + dd;
        float q0 = qv[c].x * rq * qsc[hidx], q1 = qv[c].y * rq * qsc[hidx + 1];
        float k0 = kv[c].x * rk * ksc[hidx], k1 = kv[c].y * rk * ksc[hidx + 1];
        size_t o = ((size_t)hd * N_TOK + n) * HDIM + dd;
        unsigned qo = (unsigned)f2bf(q0 * cs - q1 * sn) | ((unsigned)f2bf(q0 * sn + q1 * cs) << 16);
        unsigned ko = (unsigned)f2bf(k0 * cs - k1 * sn) | ((unsigned)f2bf(k0 * sn + k1 * cs) << 16);
        *(unsigned*)(qb + o) = qo;
        *(unsigned*)(kb + o) = ko;
    }
}

// ---- NO-SPLIT flash attention: K dbuf LDS + V direct-from-L2 (R10)
// Block = (q-tile 64 rows, head). 4 waves x 16 rows each. 46 KV tiles of 64.
// exp2-domain softmax (log2e folded into q).  Swapped QK^T: sa[j][r] =
// S[qrow=l16][key=j*16+quad*4+r] -> lane-local softmax, b64 P writes.
//
// Pipeline (2 barriers/tile, NO blocking waits):
//   top:  vmcnt(4) [K(t) resident; K(t+1) in flight — issued 2 tiles ago,
//         never blocks] ; barrier ; issue V-group0 (global->VGPR) ; QK from
//         Ks[t&1] ; barrier ; stage K(t+2)->Ks[t&1] ; softmax+P ; issue
//         V-group1 ; PV (V frags consumed from VGPRs).
// V is NEVER LDS-staged: per-head V slice (750KB) is XCD-L2 resident (the
// 552=8*69 swizzle groups same-head blocks per XCD); V loads issue >=1 softmax
// ahead of their MFMA use so L2 latency (~200cy) hides under compute.
// LDS = 2 x 16384 (K dbuf) + 8192 (P) = 40960 -> 4 blocks/CU, all 552
// blocks co-resident (hard constraint - avoids multi-round tails).
__global__ __launch_bounds__(256, 4) void k_attn_part(const unsigned short* __restrict__ qb,
                                                      const unsigned short* __restrict__ kb,
                                                      const unsigned short* __restrict__ vt,
                                                      unsigned short* __restrict__ ab) {
    __shared__ __align__(16) unsigned short Ks[2][64 * 128];  // K dbuf, linear+swz
    __shared__ __align__(16) unsigned short Ps[4][16 * 64];   // per-wave P swz

    // XCD-aware remap (bijective: 552 = 8*69)
    const int b = blockIdx.x + 46 * (int)blockIdx.y;
    const int w = (b & 7) * 69 + (b >> 3);
    const int qblk = w % 46;
    const int head = w / 46;

    const int tid = threadIdx.x, wave = tid >> 6, lane = tid & 63;
    const int quad = lane >> 4, l16 = lane & 15, x7 = l16 & 7;
    const int q0 = qblk * 64 + wave * 16;
    const unsigned short* qh = qb + (size_t)head * N_TOK * HDIM;
    const unsigned short* kh = kb + (size_t)head * N_TOK * HDIM;
    const unsigned short* vh = vt + (size_t)head * HDIM * VT_STRIDE;
    unsigned short* ps = Ps[wave];

    const int ntile = (N_TOK + 63) >> 6;               // 46 (last tile partial: 45 keys)

    int koff[4];
#pragma unroll
    for (int ks = 0; ks < 4; ks++) {
        int c = ks * 4 + quad;
        koff[ks] = ((c & 8) | ((c & 7) ^ x7)) * 8;
    }
    const int pwq = (quad >> 1), pwh = (quad & 1) * 4;

    const int krow = tid >> 4, ksw = tid & 15;
    const int kc = (ksw & 8) | ((ksw & 7) ^ (krow & 7));   // (krow+16i)&7 == krow&7
    const unsigned short* ksrc = kh + (size_t)krow * HDIM + kc * 8;
    // V direct-read base: row d = jd*16+l16, keys kb0 + ks*32 + quad*8
    const unsigned short* vbase = vh + (size_t)l16 * VT_STRIDE + quad * 8;

    // Q fragments (loaded FIRST: oldest vmcnt entries, drained by first vmcnt(4))
    bf16x8 aq[4];
    {
        int qrow = q0 + l16;
        if (qrow < N_TOK) {
#pragma unroll
            for (int ks = 0; ks < 4; ks++)
                aq[ks] = *(const bf16x8*)&qh[(size_t)qrow * HDIM + ks * 32 + quad * 8];
        } else {
#pragma unroll
            for (int ks = 0; ks < 4; ks++) aq[ks] = (bf16x8)(__bf16)0.0f;
        }
    }

    floatx4 oacc[8] = {};
    float m_l = -1e30f;
    float l_l = 0.f;

    // ---- prologue: K(0)->buf0, K(1)->buf1 (rows 0..127, all < N_TOK)
#pragma unroll
    for (int i = 0; i < 4; i++)
        gload_lds16(ksrc + (size_t)(16 * i) * HDIM, &Ks[0][(tid + 256 * i) * 8]);
#pragma unroll
    for (int i = 0; i < 4; i++)
        gload_lds16(ksrc + (size_t)(64 + 16 * i) * HDIM, &Ks[1][(tid + 256 * i) * 8]);

    for (int t = 0; t < ntile; t++) {
        const int kb0 = t * 64;
        const bool fullt = (kb0 + 64 <= N_TOK);        // false only for t=45
        const int c = t & 1;

        // ---- K(t) ready (prefetched 2 tiles ago): drain all but K(t+1)
        if (t + 1 < ntile) { asm volatile("s_waitcnt vmcnt(4)" ::: "memory"); }
        else               { asm volatile("s_waitcnt vmcnt(0)" ::: "memory"); }
        __builtin_amdgcn_sched_barrier(0);
        __builtin_amdgcn_s_barrier();

        // ---- issue V group 0 (keys kb0+quad*8, rows jd*16+l16) -> lands
        //      under QK+softmax (L2-resident)
        bf16x8 bv0[8];
#pragma unroll
        for (int jd = 0; jd < 8; jd++)
            bv0[jd] = *(const bf16x8*)&vbase[(size_t)(jd * 16) * VT_STRIDE + kb0];

        // ---- S^T = K Q^T : sa[j][r] = S[l16][kb0 + j*16 + quad*4 + r]
        floatx4 sa[4] = {};
        __builtin_amdgcn_s_setprio(1);
#pragma unroll
        for (int j = 0; j < 4; j++)
#pragma unroll
            for (int ks = 0; ks < 4; ks++) {
                bf16x8 bkf = *(const bf16x8*)&Ks[c][(j * 16 + l16) * HDIM + koff[ks]];
                sa[j] = MFMA(bkf, aq[ks], sa[j]);
            }
        __builtin_amdgcn_s_setprio(0);
        __builtin_amdgcn_s_barrier();            // all waves done reading Ks[c]

        // ---- stage K(t+2) into Ks[c] (just freed; lands by top of iter t+2)
        if (t + 2 < ntile) {
            const int kn = kb0 + 128;
            if (kn + 64 <= N_TOK) {
#pragma unroll
                for (int i = 0; i < 4; i++)
                    gload_lds16(ksrc + (size_t)(kn + 16 * i) * HDIM, &Ks[c][(tid + 256 * i) * 8]);
            } else {
#pragma unroll
                for (int i = 0; i < 4; i++) {
                    int gk = kn + krow + 16 * i;
                    gk = gk < N_TOK ? gk : N_TOK - 1;
                    gload_lds16(kh + (size_t)gk * HDIM + kc * 8, &Ks[c][(tid + 256 * i) * 8]);
                }
            }
        }

        // ---- per-lane tile max over its 16 S values, 2 quad shuffles
        float mt;
        if (fullt) {
            float m01 = fmaxf(fmaxf(sa[0][0], sa[0][1]), fmaxf(sa[0][2], sa[0][3]));
            float m23 = fmaxf(fmaxf(sa[1][0], sa[1][1]), fmaxf(sa[1][2], sa[1][3]));
            float m45 = fmaxf(fmaxf(sa[2][0], sa[2][1]), fmaxf(sa[2][2], sa[2][3]));
            float m67 = fmaxf(fmaxf(sa[3][0], sa[3][1]), fmaxf(sa[3][2], sa[3][3]));
            mt = fmaxf(fmaxf(m01, m23), fmaxf(m45, m67));
        } else {
            mt = -1e30f;
            const int kq = kb0 + quad * 4;
#pragma unroll
            for (int j = 0; j < 4; j++)
#pragma unroll
                for (int r = 0; r < 4; r++)
                    mt = fmaxf(mt, (kq + j * 16 + r < N_TOK) ? sa[j][r] : -1e30f);
        }
        mt = fmaxf(mt, __shfl_xor(mt, 16));
        mt = fmaxf(mt, __shfl_xor(mt, 32));

        // ---- defer-max (T13, THR=8 in exp2 domain)
        if (__any(mt > m_l + 8.f)) {
            float mn = fmaxf(m_l, mt);
            float alpha = exp2f(m_l - mn);
            m_l = mn;
            l_l *= alpha;
#pragma unroll
            for (int r = 0; r < 4; r++) {
                float ar = __shfl(alpha, quad * 4 + r, 16);
#pragma unroll
                for (int jd = 0; jd < 8; jd++) oacc[jd][r] *= ar;
            }
        }

        // ---- P = exp2(S - m): 4 keys/lane/j, packed bf16 -> ds_write_b64
        if (fullt) {
#pragma unroll
            for (int j = 0; j < 4; j++) {
                float p0 = exp2f(sa[j][0] - m_l), p1 = exp2f(sa[j][1] - m_l);
                float p2 = exp2f(sa[j][2] - m_l), p3 = exp2f(sa[j][3] - m_l);
                l_l += (p0 + p1) + (p2 + p3);
                uint2 wv;
                wv.x = (unsigned)__builtin_bit_cast(unsigned short, (__bf16)p0) |
                       ((unsigned)__builtin_bit_cast(unsigned short, (__bf16)p1) << 16);
                wv.y = (unsigned)__builtin_bit_cast(unsigned short, (__bf16)p2) |
                       ((unsigned)__builtin_bit_cast(unsigned short, (__bf16)p3) << 16);
                *(uint2*)&ps[l16 * 64 + (((j * 2 + pwq) ^ x7) << 3) + pwh] = wv;
            }
        } else {
            const int kq = kb0 + quad * 4;
#pragma unroll
            for (int j = 0; j < 4; j++) {
                float p[4];
#pragma unroll
                for (int r = 0; r < 4; r++) {
                    p[r] = (kq + j * 16 + r < N_TOK) ? exp2f(sa[j][r] - m_l) : 0.f;
                    l_l += p[r];
                }
                uint2 wv;
                wv.x = (unsigned)__builtin_bit_cast(unsigned short, (__bf16)p[0]) |
                       ((unsigned)__builtin_bit_cast(unsigned short, (__bf16)p[1]) << 16);
                wv.y = (unsigned)__builtin_bit_cast(unsigned short, (__bf16)p[2]) |
                       ((unsigned)__builtin_bit_cast(unsigned short, (__bf16)p[3]) << 16);
                *(uint2*)&ps[l16 * 64 + (((j * 2 + pwq) ^ x7) << 3) + pwh] = wv;
            }
        }

        // ---- issue V group 1 (keys kb0+32+quad*8) -> lands under PV group 0
        bf16x8 bv1[8];
#pragma unroll
        for (int jd = 0; jd < 8; jd++)
            bv1[jd] = *(const bf16x8*)&vbase[(size_t)(jd * 16) * VT_STRIDE + kb0 + 32];

        // ---- O += P V  (P from own-wave LDS; V from VGPRs)
        __builtin_amdgcn_s_setprio(1);
        {
            bf16x8 ap0 = *(const bf16x8*)&ps[l16 * 64 + koff[0]];
#pragma unroll
            for (int jd = 0; jd < 8; jd++)
                oacc[jd] = MFMA(ap0, bv0[jd], oacc[jd]);
            bf16x8 ap1 = *(const bf16x8*)&ps[l16 * 64 + koff[1]];
#pragma unroll
            for (int jd = 0; jd < 8; jd++)
                oacc[jd] = MFMA(ap1, bv1[jd], oacc[jd]);
        }
        __builtin_amdgcn_s_setprio(0);
        // no trailing barrier: next iter's top barrier is the only other sync
    }

    // ---- reduce l partials across quads (lanes sharing l16), normalize, store
    l_l += __shfl_xor(l_l, 16);
    l_l += __shfl_xor(l_l, 32);
    const float inv = 1.f / l_l;                       // full softmax denom for row q0+l16

#pragma unroll
    for (int r = 0; r < 4; r++) {
        const float ir = __shfl(inv, quad * 4 + r, 16);  // denom of row q0+quad*4+r
        int rg = q0 + quad * 4 + r;
        if (rg < N_TOK) {
            unsigned short* orow = ab + (size_t)rg * DMODEL + head * HDIM;
#pragma unroll
            for (int jd = 0; jd < 8; jd++)
                orow[jd * 16 + l16] = f2bf(oacc[jd][r] * ir);
        }
    }
}

// ---------------------------------------------------------------------------
extern "C" void kernel_launch(void* const* d_in, const int* in_sizes, int n_in,
                              void* d_out, int out_size, void* d_ws, size_t ws_size,
                              hipStream_t stream) {
    const float* x   = (const float*)d_in[0];
    const float* Wq  = (const float*)d_in[1];
    const float* bq  = (const float*)d_in[2];
    const float* Wk  = (const float*)d_in[3];
    const float* bk  = (const float*)d_in[4];
    const float* Wv  = (const float*)d_in[5];
    const float* bv  = (const float*)d_in[6];
    const float* Wo  = (const float*)d_in[7];
    const float* bo  = (const float*)d_in[8];
    const float* qsc = (const float*)d_in[9];
    const float* ksc = (const float*)d_in[10];
    const float* ft  = (const float*)d_in[11];
    const float* fh  = (const float*)d_in[12];
    const float* fw  = (const float*)d_in[13];

    // Layout note: ab sits BEFORE the fp32 region so the O-GEMM's A-tile
    // over-reads (rows 2925..2943) land inside d_ws (vt data), never past end.
    // QKV-GEMM A-overreads (rows 2925..3071, 451KB) land in Wt — also safe.
    char* ws = (char*)d_ws;
    unsigned short* xb   = (unsigned short*)ws; ws += (size_t)N_TOK * DMODEL * 2;          // 8,985,600
    unsigned short* Wt   = (unsigned short*)ws; ws += (size_t)4 * DMODEL * DMODEL * 2;     // 18,874,368
    unsigned short* ab   = (unsigned short*)ws; ws += (size_t)N_TOK * DMODEL * 2;          // 8,985,600
    char* qkvf_region    = ws;                  ws += (size_t)3 * N_TOK * DMODEL * 4;      // 53,913,600
    unsigned short* qkvb = (unsigned short*)ws; ws += (size_t)2 * N_TOK * DMODEL * 2;      // 17,971,200

    // Phase 1: qkvf_region holds fp32 QKV projections (53.9 MB).
    float* Qf = (float*)qkvf_region;
    float* Kf = Qf + (size_t)N_TOK * DMODEL;
    float* Vf = Qf + (size_t)2 * N_TOK * DMODEL;
    // Phase 2 (after k_postproj): vt (9.04 MB) reuses the dead Qf space;
    // Vf (read by the transpose role) is untouched by the vt writes.
    unsigned short* vtp = (unsigned short*)qkvf_region;

    unsigned short* qbp = qkvb;
    unsigned short* kbp = qkvb + (size_t)N_TOK * DMODEL;

    const int nelem = N_TOK * DMODEL;
    const int conv_blocks = (nelem / 4 + 255) / 256;                 // 4393
    k_prep<<<9216 + conv_blocks, 256, 0, stream>>>(Wq, Wk, Wv, Wo, Wt, x, xb, nelem);
    k_gemm_qkv<<<dim3(6, 12, 3), 512, 0, stream>>>(xb, Wt, bq, bk, bv, Qf, N_TOK);
    k_postproj<<<N_TOK + 4416, 256, 0, stream>>>(Qf, Kf, Vf, qsc, ksc, ft, fh, fw,
                                                 qbp, kbp, vtp);
    k_attn_part<<<dim3(46, NHEAD), 256, 0, stream>>>(qbp, kbp, vtp, ab);
    k_gemm<<<dim3(12, 23, 1), 256, 0, stream>>>(ab, Wt + (size_t)3 * DMODEL * DMODEL,
                                                bo, bo, bo, (float*)d_out, N_TOK);
}

// Round 11
// 347.745 us; speedup vs baseline: 1.7235x; 1.7235x over previous
//
#include <hip/hip_runtime.h>

// ---------------------------------------------------------------------------
// MultiHeadAttention (B=1, N=2925, D_MODEL=1536, 12 heads x 128) on gfx950.
// prep(convert x + transpose W, merged) -> QKV bf16 GEMM (256x256 dbuf
// counted-vmcnt pipeline) -> postproj(RMSNorm+RoPE Q,K + V transpose, merged)
// -> NO-SPLIT flash attention (swapped-QK^T, phase-shifted staging, epilogue
// normalization) -> O GEMM (128^2).
// R10 post-mortem: V-in-VGPR variant spilled (64 bv regs > 128-cap headroom,
// WRITE_SIZE 8.8->70MB) — reverted to the R9 attn artifact.
// ---------------------------------------------------------------------------

#define N_TOK 2925
#define DMODEL 1536
#define NHEAD 12
#define HDIM 128
#define VT_STRIDE 2944        // N_TOK padded to x64; pad MUST be zeroed (NaN hazard)

typedef __attribute__((ext_vector_type(8))) __bf16 bf16x8;
typedef __attribute__((ext_vector_type(4))) float floatx4;

#define MFMA(a, b, c) __builtin_amdgcn_mfma_f32_16x16x32_bf16((a), (b), (c), 0, 0, 0)

static __device__ __forceinline__ unsigned short f2bf(float f) {
    unsigned u = __builtin_bit_cast(unsigned, f);
    return (unsigned short)((u + 0x7fffu + ((u >> 16) & 1u)) >> 16);
}

// async global->LDS 16B/lane (emits global_load_lds_dwordx4).
// LDS dest MUST be wave-uniform-base + lane*16.
static __device__ __forceinline__ void gload_lds16(const unsigned short* g, unsigned short* l) {
    __builtin_amdgcn_global_load_lds((const __attribute__((address_space(1))) void*)g,
                                     (__attribute__((address_space(3))) void*)l, 16, 0, 0);
}

// ------------------- merged prep: W transposes (blocks 0..9215) + x convert
__global__ __launch_bounds__(256) void k_prep(const float* __restrict__ W0,
                                              const float* __restrict__ W1,
                                              const float* __restrict__ W2,
                                              const float* __restrict__ W3,
                                              unsigned short* __restrict__ Wt,
                                              const float* __restrict__ x,
                                              unsigned short* __restrict__ xb, int n) {
    const int b = blockIdx.x;
    if (b < 9216) {                                    // ---- transpose role
        __shared__ float tile[32][33];
        const int bz = b / 2304, rem = b % 2304;
        const int byi = rem / 48, bxi = rem % 48;
        const float* W = bz == 0 ? W0 : bz == 1 ? W1 : bz == 2 ? W2 : W3;
        unsigned short* out = Wt + (size_t)bz * DMODEL * DMODEL;
        const int tx = threadIdx.x & 31, ty = threadIdx.x >> 5;   // 32 x 8
        const int bx = bxi * 32, by = byi * 32;
#pragma unroll
        for (int i = 0; i < 4; i++)
            tile[ty + 8 * i][tx] = W[(size_t)(by + ty + 8 * i) * DMODEL + bx + tx];
        __syncthreads();
#pragma unroll
        for (int i = 0; i < 4; i++)
            out[(size_t)(bx + ty + 8 * i) * DMODEL + by + tx] = f2bf(tile[tx][ty + 8 * i]);
    } else {                                           // ---- convert role
        int i = ((b - 9216) * 256 + threadIdx.x) * 4;
        if (i < n) {
            float4 v = *(const float4*)(x + i);
            uint2 o;
            o.x = (unsigned)f2bf(v.x) | ((unsigned)f2bf(v.y) << 16);
            o.y = (unsigned)f2bf(v.z) | ((unsigned)f2bf(v.w) << 16);
            *(uint2*)(xb + i) = o;
        }
    }
}

// ---------------------- QKV GEMM: 256x256 tile, BK=64, 8 waves, dbuf pipeline
// LDS 128 KiB (2 bufs x (A,B) x 256x64 bf16), XOR swizzle chunk^=(row&7) on
// both sides.  Per K-tile 4 phases; staging spread {B-top,B-bot,A-lo,A-hi}
// (A halves interleaved).  Counted vmcnt(2) at W1/W2; raw s_barrier.
__global__ __launch_bounds__(512, 2) void k_gemm_qkv(const unsigned short* __restrict__ A,
                                                     const unsigned short* __restrict__ BtBase,
                                                     const float* __restrict__ b0,
                                                     const float* __restrict__ b1,
                                                     const float* __restrict__ b2,
                                                     float* __restrict__ Cbase, int M) {
    __shared__ __align__(16) unsigned short As[2][256 * 64];   // 2 x 32 KiB
    __shared__ __align__(16) unsigned short Bs[2][256 * 64];   // 2 x 32 KiB

    // XCD swizzle: nb = 216 = 8*27 exact
    const int blin = blockIdx.x + 6 * (blockIdx.y + 12 * (int)blockIdx.z);
    const int wg = (blin & 7) * 27 + (blin >> 3);
    const int z = wg / 72, rem = wg % 72, mt = rem / 6, ntile = rem % 6;
    const unsigned short* Bt = BtBase + (size_t)z * DMODEL * DMODEL;
    const float* bias = (z == 0) ? b0 : (z == 1) ? b1 : b2;
    float* C = Cbase + (size_t)z * M * DMODEL;
    const int m0 = mt * 256, n0 = ntile * 256;

    const int tid = threadIdx.x;
    const int wave = tid >> 6, lane = tid & 63, quad = lane >> 4, l16 = lane & 15;
    const int x7 = l16 & 7;
    const int wm = wave >> 2, wn = wave & 3;

    const int koff0 = ((quad) ^ x7) * 8;
    const int koff1 = ((4 + quad) ^ x7) * 8;
    const int sl = tid & 7;

    floatx4 acc[8][4] = {};

    const unsigned short* Abase = A + (size_t)m0 * DMODEL;
    const unsigned short* Bbase = Bt + (size_t)n0 * DMODEL;

    auto stageB = [&](int buf, int h, int kt) {
#pragma unroll
        for (int i = 0; i < 2; i++) {
            int d = tid + 512 * i;
            int row = h * 128 + (d >> 3);
            int c = sl ^ (row & 7);
            gload_lds16(Bbase + (size_t)row * DMODEL + kt * 64 + c * 8,
                        &Bs[buf][(row * 8 + sl) * 8]);
        }
    };
    auto stageA = [&](int buf, int h, int kt) {
#pragma unroll
        for (int i = 0; i < 2; i++) {
            int d = tid + 512 * i;
            int r7 = d >> 3;
            int row = (r7 & 63) + h * 64 + (r7 >> 6) * 128;
            int c = sl ^ (row & 7);
            gload_lds16(Abase + (size_t)row * DMODEL + kt * 64 + c * 8,
                        &As[buf][(row * 8 + sl) * 8]);
        }
    };

    stageB(0, 0, 0); stageB(0, 1, 0); stageA(0, 0, 0); stageA(0, 1, 0);

    const int NT = DMODEL / 64;                                  // 24
    for (int t = 0; t < NT; t++) {
        const int c = t & 1, sb = c ^ 1;
        const int ts = (t + 1 < NT) ? t + 1 : NT - 1;

        asm volatile("s_waitcnt vmcnt(2)" ::: "memory");
        __builtin_amdgcn_sched_barrier(0);
        __builtin_amdgcn_s_barrier();

        bf16x8 af[4], bfm[4];
#pragma unroll
        for (int m = 0; m < 4; m++)
            af[m] = *(const bf16x8*)&As[c][(wm * 128 + m * 16 + l16) * 64 + koff0];
#pragma unroll
        for (int n = 0; n < 4; n++)
            bfm[n] = *(const bf16x8*)&Bs[c][(wn * 64 + n * 16 + l16) * 64 + koff0];
        stageB(sb, 0, ts);
        __builtin_amdgcn_s_barrier();
        __builtin_amdgcn_s_setprio(1);
#pragma unroll
        for (int m = 0; m < 4; m++)
#pragma unroll
            for (int n = 0; n < 4; n++)
                acc[m][n] = MFMA(af[m], bfm[n], acc[m][n]);
        __builtin_amdgcn_s_setprio(0);
        __builtin_amdgcn_sched_barrier(0);

        asm volatile("s_waitcnt vmcnt(2)" ::: "memory");
        __builtin_amdgcn_sched_barrier(0);
        __builtin_amdgcn_s_barrier();

        bf16x8 af2[4];
#pragma unroll
        for (int m = 0; m < 4; m++)
            af2[m] = *(const bf16x8*)&As[c][(wm * 128 + 64 + m * 16 + l16) * 64 + koff0];
        stageB(sb, 1, ts);
        __builtin_amdgcn_s_barrier();
        __builtin_amdgcn_s_setprio(1);
#pragma unroll
        for (int m = 0; m < 4; m++)
#pragma unroll
            for (int n = 0; n < 4; n++)
                acc[4 + m][n] = MFMA(af2[m], bfm[n], acc[4 + m][n]);
        __builtin_amdgcn_s_setprio(0);
        __builtin_amdgcn_sched_barrier(0);

#pragma unroll
        for (int m = 0; m < 4; m++)
            af[m] = *(const bf16x8*)&As[c][(wm * 128 + m * 16 + l16) * 64 + koff1];
#pragma unroll
        for (int n = 0; n < 4; n++)
            bfm[n] = *(const bf16x8*)&Bs[c][(wn * 64 + n * 16 + l16) * 64 + koff1];
        stageA(sb, 0, ts);
        __builtin_amdgcn_s_barrier();
        __builtin_amdgcn_s_setprio(1);
#pragma unroll
        for (int m = 0; m < 4; m++)
#pragma unroll
            for (int n = 0; n < 4; n++)
                acc[m][n] = MFMA(af[m], bfm[n], acc[m][n]);
        __builtin_amdgcn_s_setprio(0);
        __builtin_amdgcn_sched_barrier(0);

#pragma unroll
        for (int m = 0; m < 4; m++)
            af2[m] = *(const bf16x8*)&As[c][(wm * 128 + 64 + m * 16 + l16) * 64 + koff1];
        stageA(sb, 1, ts);
        __builtin_amdgcn_s_barrier();
        __builtin_amdgcn_s_setprio(1);
#pragma unroll
        for (int m = 0; m < 4; m++)
#pragma unroll
            for (int n = 0; n < 4; n++)
                acc[4 + m][n] = MFMA(af2[m], bfm[n], acc[4 + m][n]);
        __builtin_amdgcn_s_setprio(0);
        __builtin_amdgcn_sched_barrier(0);
    }

#pragma unroll
    for (int n = 0; n < 4; n++) {
        int cg = n0 + wn * 64 + n * 16 + l16;
        float bv = bias[cg];
#pragma unroll
        for (int m = 0; m < 8; m++) {
            int rbase = m0 + wm * 128 + m * 16 + quad * 4;
#pragma unroll
            for (int r = 0; r < 4; r++) {
                int rg = rbase + r;
                if (rg < M) C[(size_t)rg * DMODEL + cg] = acc[m][n][r] + bv;
            }
        }
    }
}

// ------------------------------------------------------------ bf16 MFMA GEMM
// m97 structure (used for the O projection): unpadded stride-32 LDS tiles.
__global__ __launch_bounds__(256, 3) void k_gemm(const unsigned short* __restrict__ A,
                                                 const unsigned short* __restrict__ BtBase,
                                                 const float* __restrict__ b0,
                                                 const float* __restrict__ b1,
                                                 const float* __restrict__ b2,
                                                 float* __restrict__ Cbase, int M) {
    const int nbx = gridDim.x, nxy = gridDim.x * gridDim.y;
    const int nb = nxy * gridDim.z;
    const int blin = blockIdx.x + nbx * (blockIdx.y + gridDim.y * blockIdx.z);
    const int q8 = nb >> 3, r8 = nb & 7, xcd = blin & 7, idx = blin >> 3;
    const int wg = (xcd < r8) ? xcd * (q8 + 1) + idx
                              : r8 * (q8 + 1) + (xcd - r8) * q8 + idx;
    const int z = wg / nxy;
    const int rem = wg % nxy;
    const int bym = rem / nbx, bxn = rem % nbx;

    const unsigned short* Bt = BtBase + (size_t)z * DMODEL * DMODEL;
    const float* bias = (z == 0) ? b0 : (z == 1) ? b1 : b2;
    float* C = Cbase + (size_t)z * M * DMODEL;

    __shared__ __align__(16) unsigned short As[128 * 32];
    __shared__ __align__(16) unsigned short Bs[128 * 32];

    const int tid = threadIdx.x;
    const int wave = tid >> 6, lane = tid & 63, quad = lane >> 4, l16 = lane & 15;
    const int wr = wave >> 1, wc = wave & 1;
    const int m0 = bym * 128, n0 = bxn * 128;
    const int r4 = tid >> 2, c4 = (tid & 3) * 8;

    floatx4 acc[4][4] = {};

    for (int k0 = 0; k0 < DMODEL; k0 += 32) {
        gload_lds16(A + (size_t)(m0 + r4) * DMODEL + k0 + c4,       &As[r4 * 32 + c4]);
        gload_lds16(A + (size_t)(m0 + r4 + 64) * DMODEL + k0 + c4,  &As[(r4 + 64) * 32 + c4]);
        gload_lds16(Bt + (size_t)(n0 + r4) * DMODEL + k0 + c4,      &Bs[r4 * 32 + c4]);
        gload_lds16(Bt + (size_t)(n0 + r4 + 64) * DMODEL + k0 + c4, &Bs[(r4 + 64) * 32 + c4]);
        __syncthreads();

        bf16x8 af[4], bfm[4];
#pragma unroll
        for (int i = 0; i < 4; i++)
            af[i] = *(const bf16x8*)&As[(wr * 64 + i * 16 + l16) * 32 + quad * 8];
#pragma unroll
        for (int j = 0; j < 4; j++)
            bfm[j] = *(const bf16x8*)&Bs[(wc * 64 + j * 16 + l16) * 32 + quad * 8];
#pragma unroll
        for (int i = 0; i < 4; i++)
#pragma unroll
            for (int j = 0; j < 4; j++)
                acc[i][j] = MFMA(af[i], bfm[j], acc[i][j]);
        __syncthreads();
    }

#pragma unroll
    for (int j = 0; j < 4; j++) {
        int cg = n0 + wc * 64 + j * 16 + l16;
        float bv = bias[cg];
#pragma unroll
        for (int i = 0; i < 4; i++) {
            int rbase = m0 + wr * 64 + i * 16 + quad * 4;
#pragma unroll
            for (int r = 0; r < 4; r++) {
                int rg = rbase + r;
                if (rg < M) C[(size_t)rg * DMODEL + cg] = acc[i][j][r] + bv;
            }
        }
    }
}

// ---------- merged postproj: RMSNorm+3D RoPE (blocks 0..2924) + V transpose
__global__ __launch_bounds__(256) void k_postproj(const float* __restrict__ Qf,
                                                  const float* __restrict__ Kf,
                                                  const float* __restrict__ Vf,
                                                  const float* __restrict__ qsc,
                                                  const float* __restrict__ ksc,
                                                  const float* __restrict__ ft,
                                                  const float* __restrict__ fh,
                                                  const float* __restrict__ fw,
                                                  unsigned short* __restrict__ qb,
                                                  unsigned short* __restrict__ kb,
                                                  unsigned short* __restrict__ vt) {
    const int blk = blockIdx.x;
    if (blk >= N_TOK) {                                // ---- V transpose role
        __shared__ float tile[32][33];
        const int v = blk - N_TOK;                     // 0..4415
        const int bxi = v % 92, byi = (v / 92) % 4, head = v / 368;
        const int t0 = bxi * 32, d0 = byi * 32;
        const int tx = threadIdx.x & 31, ty = threadIdx.x >> 5;   // 32 x 8
#pragma unroll
        for (int i = 0; i < 4; i++) {
            int t = t0 + ty + 8 * i;
            tile[ty + 8 * i][tx] = (t < N_TOK) ? Vf[(size_t)t * DMODEL + head * HDIM + d0 + tx] : 0.f;
        }
        __syncthreads();
        int t = t0 + tx;                               // < VT_STRIDE always
#pragma unroll
        for (int i = 0; i < 4; i++)
            vt[((size_t)head * HDIM + d0 + ty + 8 * i) * VT_STRIDE + t] = f2bf(tile[tx][ty + 8 * i]);
        return;
    }

    // ---- norm+rope role
    const int n = blk;
    const int tid = threadIdx.x, wave = tid >> 6, lane = tid & 63;
    const int t_i = n / 225, rem = n % 225, h_i = rem / 15, w_i = rem % 15;
    const float att_scale = 0.08838834764831845f * 1.4426950408889634f;  // 1/sqrt(128)*log2e

    float2 qv[3], kv[3];
    float sq = 0.f, sk = 0.f;
#pragma unroll
    for (int c = 0; c < 3; c++) {
        int p = tid + 256 * c;
        qv[c] = *(const float2*)(Qf + (size_t)n * DMODEL + 2 * p);
        kv[c] = *(const float2*)(Kf + (size_t)n * DMODEL + 2 * p);
        sq += qv[c].x * qv[c].x + qv[c].y * qv[c].y;
        sk += kv[c].x * kv[c].x + kv[c].y * kv[c].y;
    }
#pragma unroll
    for (int off = 32; off >= 1; off >>= 1) {
        sq += __shfl_xor(sq, off, 64);
        sk += __shfl_xor(sk, off, 64);
    }
    __shared__ float red[2][4];
    if (lane == 0) { red[0][wave] = sq; red[1][wave] = sk; }
    __syncthreads();
    sq = red[0][0] + red[0][1] + red[0][2] + red[0][3];
    sk = red[1][0] + red[1][1] + red[1][2] + red[1][3];
    const float rq = rsqrtf(sq * (1.f / 1536.f) + 1e-6f) * att_scale;
    const float rk = rsqrtf(sk * (1.f / 1536.f) + 1e-6f);

#pragma unroll
    for (int c = 0; c < 3; c++) {
        int p = tid + 256 * c;
        int hd = p >> 6, pl = p & 63, dd = 2 * pl;
        float cs, sn;
        if (pl < 22)      { cs = ft[t_i * 44 + 2 * pl];        sn = ft[t_i * 44 + 2 * pl + 1]; }
        else if (pl < 43) { int pp = pl - 22; cs = fh[h_i * 42 + 2 * pp]; sn = fh[h_i * 42 + 2 * pp + 1]; }
        else              { int pp = pl - 43; cs = fw[w_i * 42 + 2 * pp]; sn = fw[w_i * 42 + 2 * pp + 1]; }
        int hidx = hd * 128 + dd;
        float q0 = qv[c].x * rq * qsc[hidx], q1 = qv[c].y * rq * qsc[hidx + 1];
        float k0 = kv[c].x * rk * ksc[hidx], k1 = kv[c].y * rk * ksc[hidx + 1];
        size_t o = ((size_t)hd * N_TOK + n) * HDIM + dd;
        unsigned qo = (unsigned)f2bf(q0 * cs - q1 * sn) | ((unsigned)f2bf(q0 * sn + q1 * cs) << 16);
        unsigned ko = (unsigned)f2bf(k0 * cs - k1 * sn) | ((unsigned)f2bf(k0 * sn + k1 * cs) << 16);
        *(unsigned*)(qb + o) = qo;
        *(unsigned*)(kb + o) = ko;
    }
}

// ---------------- NO-SPLIT flash attention, phase-shifted async pipeline (R9)
// Block = (q-tile 64 rows, head). 4 waves x 16 rows each. 46 KV tiles of 64.
// exp2-domain softmax (log2e folded into q).  Swapped QK^T: sa[j][r] =
// S[qrow=l16][key=j*16+quad*4+r] -> lane-local softmax, b64 P writes.
// Epilogue: normalize by 1/l and write bf16 ab directly (no combine pass).
//
// Pipeline (counted vmcnt, raw barriers):
//   top:   vmcnt(4) [drain Q+K(t), V(t) in flight] ; barrier ; QK
//   post-QK barrier ; issue K(t+1)
//   pre-PV: vmcnt(4) [drain V(t), K(t+1) in flight] ; barrier ; PV
//   post-PV barrier ; issue V(t+1)
// XCD swizzle: 552 blocks = 8 x 69 (exact).
// LDS = 16384 (K) + 16384 (V^T) + 8192 (P) = 40960 -> 4 blocks/CU.
__global__ __launch_bounds__(256, 4) void k_attn_part(const unsigned short* __restrict__ qb,
                                                      const unsigned short* __restrict__ kb,
                                                      const unsigned short* __restrict__ vt,
                                                      unsigned short* __restrict__ ab) {
    __shared__ __align__(16) unsigned short Ks[64 * 128];   // [key][d]   linear+swz
    __shared__ __align__(16) unsigned short Vs[128 * 64];   // [d][key]   linear+swz
    __shared__ __align__(16) unsigned short Ps[4][16 * 64]; // per-wave P [qrow][key] swz

    // XCD-aware remap (bijective: 552 = 8*69)
    const int b = blockIdx.x + 46 * (int)blockIdx.y;
    const int w = (b & 7) * 69 + (b >> 3);
    const int qblk = w % 46;
    const int head = w / 46;

    const int tid = threadIdx.x, wave = tid >> 6, lane = tid & 63;
    const int quad = lane >> 4, l16 = lane & 15, x7 = l16 & 7;
    const int q0 = qblk * 64 + wave * 16;
    const unsigned short* qh = qb + (size_t)head * N_TOK * HDIM;
    const unsigned short* kh = kb + (size_t)head * N_TOK * HDIM;
    const unsigned short* vh = vt + (size_t)head * HDIM * VT_STRIDE;
    unsigned short* ps = Ps[wave];

    const int ntile = (N_TOK + 63) >> 6;               // 46 (last tile partial: 45 keys)

    int koff[4];
#pragma unroll
    for (int ks = 0; ks < 4; ks++) {
        int c = ks * 4 + quad;
        koff[ks] = ((c & 8) | ((c & 7) ^ x7)) * 8;
    }
    const int pwq = (quad >> 1), pwh = (quad & 1) * 4;

    const int krow = tid >> 4, ksw = tid & 15;
    const int kc = (ksw & 8) | ((ksw & 7) ^ (krow & 7));   // (krow+16i)&7 == krow&7
    const int vd = tid >> 3, vsw = tid & 7;
    const int vc = vsw ^ (vd & 7);                          // (vd+32i)&7 == vd&7
    const unsigned short* ksrc = kh + (size_t)krow * HDIM + kc * 8;
    const unsigned short* vsrc = vh + (size_t)vd * VT_STRIDE + vc * 8;

    bf16x8 aq[4];
    {
        int qrow = q0 + l16;
        if (qrow < N_TOK) {
#pragma unroll
            for (int ks = 0; ks < 4; ks++)
                aq[ks] = *(const bf16x8*)&qh[(size_t)qrow * HDIM + ks * 32 + quad * 8];
        } else {
#pragma unroll
            for (int ks = 0; ks < 4; ks++) aq[ks] = (bf16x8)(__bf16)0.0f;
        }
    }

    floatx4 oacc[8] = {};
    float m_l = -1e30f;
    float l_l = 0.f;

    // ---- prologue: issue K(0) then V(0)  (tile 0 is always full)
#pragma unroll
    for (int i = 0; i < 4; i++)
        gload_lds16(ksrc + (size_t)(16 * i) * HDIM, &Ks[(tid + 256 * i) * 8]);
#pragma unroll
    for (int i = 0; i < 4; i++)
        gload_lds16(vsrc + (size_t)(32 * i) * VT_STRIDE, &Vs[(tid + 256 * i) * 8]);

    for (int t = 0; t < ntile; t++) {
        const int kb0 = t * 64;
        const bool fullt = (kb0 + 64 <= N_TOK);        // false only for t=45
        const bool has_next = (t + 1 < ntile);

        asm volatile("s_waitcnt vmcnt(4)" ::: "memory");
        __builtin_amdgcn_sched_barrier(0);
        __builtin_amdgcn_s_barrier();

        floatx4 sa[4] = {};
        __builtin_amdgcn_s_setprio(1);
#pragma unroll
        for (int j = 0; j < 4; j++)
#pragma unroll
            for (int ks = 0; ks < 4; ks++) {
                bf16x8 bkf = *(const bf16x8*)&Ks[(j * 16 + l16) * HDIM + koff[ks]];
                sa[j] = MFMA(bkf, aq[ks], sa[j]);
            }
        __builtin_amdgcn_s_setprio(0);
        __builtin_amdgcn_s_barrier();            // all waves done reading Ks

        if (has_next) {
            const int kn = kb0 + 64;
            if (kn + 64 <= N_TOK) {
#pragma unroll
                for (int i = 0; i < 4; i++)
                    gload_lds16(ksrc + (size_t)(kn + 16 * i) * HDIM, &Ks[(tid + 256 * i) * 8]);
            } else {
#pragma unroll
                for (int i = 0; i < 4; i++) {
                    int gk = kn + krow + 16 * i;
                    gk = gk < N_TOK ? gk : N_TOK - 1;
                    gload_lds16(kh + (size_t)gk * HDIM + kc * 8, &Ks[(tid + 256 * i) * 8]);
                }
            }
        }

        float mt;
        if (fullt) {
            float m01 = fmaxf(fmaxf(sa[0][0], sa[0][1]), fmaxf(sa[0][2], sa[0][3]));
            float m23 = fmaxf(fmaxf(sa[1][0], sa[1][1]), fmaxf(sa[1][2], sa[1][3]));
            float m45 = fmaxf(fmaxf(sa[2][0], sa[2][1]), fmaxf(sa[2][2], sa[2][3]));
            float m67 = fmaxf(fmaxf(sa[3][0], sa[3][1]), fmaxf(sa[3][2], sa[3][3]));
            mt = fmaxf(fmaxf(m01, m23), fmaxf(m45, m67));
        } else {
            mt = -1e30f;
            const int kq = kb0 + quad * 4;
#pragma unroll
            for (int j = 0; j < 4; j++)
#pragma unroll
                for (int r = 0; r < 4; r++)
                    mt = fmaxf(mt, (kq + j * 16 + r < N_TOK) ? sa[j][r] : -1e30f);
        }
        mt = fmaxf(mt, __shfl_xor(mt, 16));
        mt = fmaxf(mt, __shfl_xor(mt, 32));

        if (__any(mt > m_l + 8.f)) {
            float mn = fmaxf(m_l, mt);
            float alpha = exp2f(m_l - mn);
            m_l = mn;
            l_l *= alpha;
#pragma unroll
            for (int r = 0; r < 4; r++) {
                float ar = __shfl(alpha, quad * 4 + r, 16);
#pragma unroll
                for (int jd = 0; jd < 8; jd++) oacc[jd][r] *= ar;
            }
        }

        if (fullt) {
#pragma unroll
            for (int j = 0; j < 4; j++) {
                float p0 = exp2f(sa[j][0] - m_l), p1 = exp2f(sa[j][1] - m_l);
                float p2 = exp2f(sa[j][2] - m_l), p3 = exp2f(sa[j][3] - m_l);
                l_l += (p0 + p1) + (p2 + p3);
                uint2 wv;
                wv.x = (unsigned)__builtin_bit_cast(unsigned short, (__bf16)p0) |
                       ((unsigned)__builtin_bit_cast(unsigned short, (__bf16)p1) << 16);
                wv.y = (unsigned)__builtin_bit_cast(unsigned short, (__bf16)p2) |
                       ((unsigned)__builtin_bit_cast(unsigned short, (__bf16)p3) << 16);
                *(uint2*)&ps[l16 * 64 + (((j * 2 + pwq) ^ x7) << 3) + pwh] = wv;
            }
        } else {
            const int kq = kb0 + quad * 4;
#pragma unroll
            for (int j = 0; j < 4; j++) {
                float p[4];
#pragma unroll
                for (int r = 0; r < 4; r++) {
                    p[r] = (kq + j * 16 + r < N_TOK) ? exp2f(sa[j][r] - m_l) : 0.f;
                    l_l += p[r];
                }
                uint2 wv;
                wv.x = (unsigned)__builtin_bit_cast(unsigned short, (__bf16)p[0]) |
                       ((unsigned)__builtin_bit_cast(unsigned short, (__bf16)p[1]) << 16);
                wv.y = (unsigned)__builtin_bit_cast(unsigned short, (__bf16)p[2]) |
                       ((unsigned)__builtin_bit_cast(unsigned short, (__bf16)p[3]) << 16);
                *(uint2*)&ps[l16 * 64 + (((j * 2 + pwq) ^ x7) << 3) + pwh] = wv;
            }
        }

        if (has_next) { asm volatile("s_waitcnt vmcnt(4)" ::: "memory"); }
        else          { asm volatile("s_waitcnt vmcnt(0)" ::: "memory"); }
        __builtin_amdgcn_sched_barrier(0);
        __builtin_amdgcn_s_barrier();

        __builtin_amdgcn_s_setprio(1);
#pragma unroll
        for (int ks = 0; ks < 2; ks++) {
            bf16x8 ap = *(const bf16x8*)&ps[l16 * 64 + koff[ks]];
#pragma unroll
            for (int jd = 0; jd < 8; jd++) {
                bf16x8 bvf = *(const bf16x8*)&Vs[(jd * 16 + l16) * 64 + koff[ks]];
                oacc[jd] = MFMA(ap, bvf, oacc[jd]);
            }
        }
        __builtin_amdgcn_s_setprio(0);
        __builtin_amdgcn_s_barrier();            // all waves done reading Vs

        if (has_next) {
            const int kn = kb0 + 64;
#pragma unroll
            for (int i = 0; i < 4; i++)
                gload_lds16(vsrc + (size_t)(32 * i) * VT_STRIDE + kn, &Vs[(tid + 256 * i) * 8]);
        }
    }

    // ---- reduce l partials across quads (lanes sharing l16), normalize, store
    l_l += __shfl_xor(l_l, 16);
    l_l += __shfl_xor(l_l, 32);
    const float inv = 1.f / l_l;                       // full softmax denom for row q0+l16

#pragma unroll
    for (int r = 0; r < 4; r++) {
        const float ir = __shfl(inv, quad * 4 + r, 16);  // denom of row q0+quad*4+r
        int rg = q0 + quad * 4 + r;
        if (rg < N_TOK) {
            unsigned short* orow = ab + (size_t)rg * DMODEL + head * HDIM;
#pragma unroll
            for (int jd = 0; jd < 8; jd++)
                orow[jd * 16 + l16] = f2bf(oacc[jd][r] * ir);
        }
    }
}

// ---------------------------------------------------------------------------
extern "C" void kernel_launch(void* const* d_in, const int* in_sizes, int n_in,
                              void* d_out, int out_size, void* d_ws, size_t ws_size,
                              hipStream_t stream) {
    const float* x   = (const float*)d_in[0];
    const float* Wq  = (const float*)d_in[1];
    const float* bq  = (const float*)d_in[2];
    const float* Wk  = (const float*)d_in[3];
    const float* bk  = (const float*)d_in[4];
    const float* Wv  = (const float*)d_in[5];
    const float* bv  = (const float*)d_in[6];
    const float* Wo  = (const float*)d_in[7];
    const float* bo  = (const float*)d_in[8];
    const float* qsc = (const float*)d_in[9];
    const float* ksc = (const float*)d_in[10];
    const float* ft  = (const float*)d_in[11];
    const float* fh  = (const float*)d_in[12];
    const float* fw  = (const float*)d_in[13];

    // Layout note: ab sits BEFORE the fp32 region so the O-GEMM's A-tile
    // over-reads (rows 2925..2943) land inside d_ws (vt data), never past end.
    // QKV-GEMM A-overreads (rows 2925..3071, 451KB) land in Wt — also safe.
    char* ws = (char*)d_ws;
    unsigned short* xb   = (unsigned short*)ws; ws += (size_t)N_TOK * DMODEL * 2;          // 8,985,600
    unsigned short* Wt   = (unsigned short*)ws; ws += (size_t)4 * DMODEL * DMODEL * 2;     // 18,874,368
    unsigned short* ab   = (unsigned short*)ws; ws += (size_t)N_TOK * DMODEL * 2;          // 8,985,600
    char* qkvf_region    = ws;                  ws += (size_t)3 * N_TOK * DMODEL * 4;      // 53,913,600
    unsigned short* qkvb = (unsigned short*)ws; ws += (size_t)2 * N_TOK * DMODEL * 2;      // 17,971,200

    // Phase 1: qkvf_region holds fp32 QKV projections (53.9 MB).
    float* Qf = (float*)qkvf_region;
    float* Kf = Qf + (size_t)N_TOK * DMODEL;
    float* Vf = Qf + (size_t)2 * N_TOK * DMODEL;
    // Phase 2 (after k_postproj): vt (9.04 MB) reuses the dead Qf space;
    // Vf (read by the transpose role) is untouched by the vt writes.
    unsigned short* vtp = (unsigned short*)qkvf_region;

    unsigned short* qbp = qkvb;
    unsigned short* kbp = qkvb + (size_t)N_TOK * DMODEL;

    const int nelem = N_TOK * DMODEL;
    const int conv_blocks = (nelem / 4 + 255) / 256;                 // 4393
    k_prep<<<9216 + conv_blocks, 256, 0, stream>>>(Wq, Wk, Wv, Wo, Wt, x, xb, nelem);
    k_gemm_qkv<<<dim3(6, 12, 3), 512, 0, stream>>>(xb, Wt, bq, bk, bv, Qf, N_TOK);
    k_postproj<<<N_TOK + 4416, 256, 0, stream>>>(Qf, Kf, Vf, qsc, ksc, ft, fh, fw,
                                                 qbp, kbp, vtp);
    k_attn_part<<<dim3(46, NHEAD), 256, 0, stream>>>(qbp, kbp, vtp, ab);
    k_gemm<<<dim3(12, 23, 1), 256, 0, stream>>>(ab, Wt + (size_t)3 * DMODEL * DMODEL,
                                                bo, bo, bo, (float*)d_out, N_TOK);
}